// Round 13
// baseline (409.104 us; speedup 1.0000x reference)
//
#include <hip/hip_runtime.h>
#include <hip/hip_bf16.h>

// Problem constants (B=4, L=1024, D=1024, H=16, Dh=64, MAX_LEN=150)
#define BB 4
#define LL 1024
#define DD 1024
#define HH 16
#define DH 64
#define NPOS 301      // 2*MAX_LEN+1
#define MAXL 150
#define NEG_INF -1e30f

typedef __attribute__((ext_vector_type(4))) float f32x4;
typedef __attribute__((ext_vector_type(8))) short short8;

__device__ inline unsigned short f2b(float x) {
    __hip_bfloat16 h = __float2bfloat16(x);
    return *reinterpret_cast<unsigned short*>(&h);
}
__device__ inline unsigned pack2(float a, float b) {
    return (unsigned)f2b(a) | ((unsigned)f2b(b) << 16);
}
__device__ inline float b2f(unsigned short u) {
    return __uint_as_float((unsigned)u << 16);
}

// Load 8 contiguous elements as bf16x8, converting from f32 when F32=true.
template <bool F32>
__device__ inline short8 ld8(const void* p, size_t off) {
    if constexpr (F32) {
        const float* q = (const float*)p + off;
        float4 a = *reinterpret_cast<const float4*>(q);
        float4 b = *reinterpret_cast<const float4*>(q + 4);
        short8 r;
        r[0] = (short)f2b(a.x); r[1] = (short)f2b(a.y);
        r[2] = (short)f2b(a.z); r[3] = (short)f2b(a.w);
        r[4] = (short)f2b(b.x); r[5] = (short)f2b(b.y);
        r[6] = (short)f2b(b.z); r[7] = (short)f2b(b.w);
        return r;
    } else {
        return *reinterpret_cast<const short8*>((const unsigned short*)p + off);
    }
}

// ---------------------------------------------------------------------------
// Mask bit-pack: mask[b][q][k] (nonzero = masked) -> one bit per element.
// ---------------------------------------------------------------------------
__global__ __launch_bounds__(256) void pack_mask(const int* __restrict__ mask,
                                                 unsigned long long* __restrict__ bits)
{
    const int wid = (blockIdx.x * 256 + threadIdx.x) >> 6;   // global wave id
    const int lane = threadIdx.x & 63;
    const int v = mask[(size_t)wid * 64 + lane];
    const unsigned long long b = __ballot(v != 0);
    if (lane == 0) bits[wid] = b;
}

// ---------------------------------------------------------------------------
// bf16 MFMA GEMM: C = (A @ W^T + bias) * oscale.  (validated rounds 7-12)
// A/W may be f32 -- converted to bf16 in-register during LDS staging.
// Tile 128(M) x 64(N), BK=32, 4 waves (2x2), wave owns 64x32; padded LDS.
// EPI 0: f32 [M][N]; EPI 1: bf16 [bh][l][dh]; EPI 2: bf16 [bh][dh][l];
// EPI 3: bf16 plain [M][N] (GN guards N).
// ---------------------------------------------------------------------------
template <int EPI, bool GN, bool AF32, bool WF32>
__global__ __launch_bounds__(256) void gemm_mfma(
    const void* __restrict__ A, const void* __restrict__ W,
    const float* __restrict__ bias, void* __restrict__ Cout,
    int M, int N, int K, float oscale)
{
    __shared__ alignas(16) unsigned short As[128 * 40];
    __shared__ alignas(16) unsigned short Bs[64 * 40];
    const int tid = threadIdx.x;
    const int w = tid >> 6, lane = tid & 63;
    const int wr = w >> 1, wc = w & 1;
    const int g = lane >> 4, fr = lane & 15;
    const int m0 = blockIdx.y * 128;
    const int n0 = blockIdx.x * 64;

    f32x4 acc[4][2];
#pragma unroll
    for (int i = 0; i < 4; ++i)
#pragma unroll
        for (int j = 0; j < 2; ++j) acc[i][j] = (f32x4){0.f, 0.f, 0.f, 0.f};

    const int arow0 = tid >> 2, agg = tid & 3;
    for (int k0 = 0; k0 < K; k0 += 32) {
        {
            short8 v0 = ld8<AF32>(A, (size_t)(m0 + arow0) * K + k0 + agg * 8);
            short8 v1 = ld8<AF32>(A, (size_t)(m0 + arow0 + 64) * K + k0 + agg * 8);
            int nr = n0 + arow0;
            if (GN && nr >= N) nr = N - 1;
            short8 bv = ld8<WF32>(W, (size_t)nr * K + k0 + agg * 8);
            *reinterpret_cast<short8*>(&As[arow0 * 40 + agg * 8]) = v0;
            *reinterpret_cast<short8*>(&As[(arow0 + 64) * 40 + agg * 8]) = v1;
            *reinterpret_cast<short8*>(&Bs[arow0 * 40 + agg * 8]) = bv;
        }
        __syncthreads();
        short8 af[4], bf[2];
#pragma unroll
        for (int i = 0; i < 4; ++i)
            af[i] = *reinterpret_cast<const short8*>(
                &As[(wr * 64 + i * 16 + fr) * 40 + g * 8]);
#pragma unroll
        for (int j = 0; j < 2; ++j)
            bf[j] = *reinterpret_cast<const short8*>(
                &Bs[(wc * 32 + j * 16 + fr) * 40 + g * 8]);
#pragma unroll
        for (int i = 0; i < 4; ++i)
#pragma unroll
            for (int j = 0; j < 2; ++j)
                acc[i][j] = __builtin_amdgcn_mfma_f32_16x16x32_bf16(
                    af[i], bf[j], acc[i][j], 0, 0, 0);
        __syncthreads();
    }

#pragma unroll
    for (int i = 0; i < 4; ++i) {
#pragma unroll
        for (int j = 0; j < 2; ++j) {
#pragma unroll
            for (int r = 0; r < 4; ++r) {
                const int row = m0 + wr * 64 + i * 16 + g * 4 + r;
                const int col = n0 + wc * 32 + j * 16 + fr;
                if (GN && col >= N) continue;
                const float val = (acc[i][j][r] + (bias ? bias[col] : 0.f)) * oscale;
                if (EPI == 0) {
                    ((float*)Cout)[(size_t)row * N + col] = val;
                } else if (EPI == 1) {
                    const int b = row >> 10, l = row & 1023, hh = col >> 6, dh = col & 63;
                    ((unsigned short*)Cout)[(((size_t)(b * HH + hh)) * LL + l) * DH + dh] = f2b(val);
                } else if (EPI == 2) {
                    const int b = row >> 10, l = row & 1023, hh = col >> 6, dh = col & 63;
                    ((unsigned short*)Cout)[(((size_t)(b * HH + hh)) * DH + dh) * LL + l] = f2b(val);
                } else {
                    ((unsigned short*)Cout)[(size_t)row * N + col] = f2b(val);
                }
            }
        }
    }
}

// ---------------------------------------------------------------------------
// MFMA attention, round 13: OCCUPANCY PUSH. r9-r12 established the kernel is
// stall-bound (VALU 25%, MFMA 4%, HBM 4%) with only ~2 waves/SIMD hiding
// latency; VGPR=72 sits just over the 64-reg occupancy cliff (m69). Changes:
//  * scores/exp computed IN PLACE in s (sv[4][4] eliminated, -16 peak VGPR)
//  * strict-in-band fast path in the qpos gather (no clamp temps)
//  * __launch_bounds__(256, 8) pins VGPR <= 64 -> 32 waves/CU co-resident.
// Structure otherwise = r12 split-K (2 q-groups x 2 k-halves, LDS merge).
// ---------------------------------------------------------------------------
__global__ __launch_bounds__(256, 8) void attn_mfma(
    const unsigned short* __restrict__ qbf,   // [bh][l][dh] bf16 (scaled 1/8)
    const unsigned short* __restrict__ kbf,   // [bh][l][dh] bf16
    const unsigned short* __restrict__ vT,    // [bh][dh][l] bf16
    const unsigned short* __restrict__ qpos,  // [bh*L][301] bf16 (scaled 1/8)
    const unsigned long long* __restrict__ mbits, // [b][q][L/64] bit-mask
    unsigned short* __restrict__ outb)        // [b][l][D] bf16
{
    const int bh = blockIdx.x;                // fast dim -> same-bh on one XCD
    const int qblk = blockIdx.y;
    const int b = bh >> 4, h = bh & 15;
    const int tid = threadIdx.x;
    const int w = tid >> 6;                   // 0..3
    const int qh = w & 1;                     // q-group
    const int kh = w >> 1;                    // k-half
    const int lane = tid & 63;
    const int g = lane >> 4;
    const int qc = lane & 15;
    const int gq = qblk * 32 + qh * 16 + qc;

    __shared__ alignas(16) unsigned char Plds[4 * 2048];
    __shared__ float Mrg[2][64][18];          // (o[16], m, l) from kh=1 waves
    unsigned char* myP = Plds + w * 2048 + qc * 128;
    const int swz = (qc & 7) << 4;

    const unsigned short* qrow = qbf + ((size_t)bh * LL + gq) * DH;
    const short8 qf0 = *reinterpret_cast<const short8*>(qrow + g * 8);
    const short8 qf1 = *reinterpret_cast<const short8*>(qrow + g * 8 + 32);

    const unsigned short* kb0 = kbf + (size_t)bh * LL * DH;
    const unsigned short* vb0 = vT + (size_t)bh * DH * LL;
    const unsigned long long* mwp = mbits + ((size_t)b * LL + gq) * (LL / 64);
    const unsigned short* qpr = qpos + ((size_t)bh * LL + gq) * NPOS;
    const float c_left = b2f(qpr[300]);       // rel <= -150
    const float c_right = b2f(qpr[299]);      // rel >= +150

    float mrun = -3.0e38f, lrun = 0.f;
    f32x4 o[4];
#pragma unroll
    for (int m = 0; m < 4; ++m) o[m] = (f32x4){0.f, 0.f, 0.f, 0.f};

    // 8 tiles per wave, interleaved across k-halves
    for (int it = 0; it < 8; ++it) {
        const int kt = kh * 64 + it * 128;

        // ---- S^T = K . Q^T ----
        f32x4 s[4];
#pragma unroll
        for (int m = 0; m < 4; ++m) s[m] = (f32x4){0.f, 0.f, 0.f, 0.f};
#pragma unroll
        for (int m = 0; m < 4; ++m) {
            const unsigned short* krow = kb0 + (size_t)(kt + m * 16 + qc) * DH + g * 8;
            short8 a0 = *reinterpret_cast<const short8*>(krow);
            short8 a1 = *reinterpret_cast<const short8*>(krow + 32);
            s[m] = __builtin_amdgcn_mfma_f32_16x16x32_bf16(a0, qf0, s[m], 0, 0, 0);
            s[m] = __builtin_amdgcn_mfma_f32_16x16x32_bf16(a1, qf1, s[m], 0, 0, 0);
        }

        // ---- scores in place: banded qpos + bit-mask ----
        const unsigned long long mw = mwp[kt >> 6];
        float tmax = -3.0e38f;
#pragma unroll
        for (int m = 0; m < 4; ++m) {
            const int kb = kt + m * 16 + g * 4;
            const unsigned msub = (unsigned)(mw >> (m * 16 + g * 4)) & 0xFu;
            const int p0 = kb - gq + 149;     // unclipped idx of r=0
            float rp0, rp1, rp2, rp3;
            if (p0 > 299) {                   // whole run right-saturated
                rp0 = rp1 = rp2 = rp3 = c_right;
            } else if (p0 < -3) {             // whole run left-saturated
                rp0 = rp1 = rp2 = rp3 = c_left;
            } else if (p0 >= 0 && p0 <= 296) { // strictly in band: no clamps
                rp0 = b2f(qpr[p0]);     rp1 = b2f(qpr[p0 + 1]);
                rp2 = b2f(qpr[p0 + 2]); rp3 = b2f(qpr[p0 + 3]);
            } else {                          // straddling band edge (rare)
                int i0 = p0 < 0 ? 300 : p0;
                int i1 = p0 + 1 < 0 ? 300 : (p0 + 1 > 299 ? 299 : p0 + 1);
                int i2 = p0 + 2 < 0 ? 300 : (p0 + 2 > 299 ? 299 : p0 + 2);
                int i3 = p0 + 3 > 299 ? 299 : p0 + 3;
                rp0 = b2f(qpr[i0]); rp1 = b2f(qpr[i1]);
                rp2 = b2f(qpr[i2]); rp3 = b2f(qpr[i3]);
            }
#pragma unroll
            for (int r = 0; r < 4; ++r) {
                const float rp = (r == 0 ? rp0 : r == 1 ? rp1 : r == 2 ? rp2 : rp3);
                float x = s[m][r] + rp;       // both pre-scaled by 1/8
                x = (msub >> r) & 1 ? NEG_INF : x;
                s[m][r] = x;
                tmax = fmaxf(tmax, x);
            }
        }

        // ---- online softmax (in-register, in-place exp) ----
        tmax = fmaxf(tmax, __shfl_xor(tmax, 16));
        tmax = fmaxf(tmax, __shfl_xor(tmax, 32));
        const float nm = fmaxf(mrun, tmax);
        const float al = __expf(mrun - nm);
        mrun = nm;
        float ls = 0.f;
#pragma unroll
        for (int m = 0; m < 4; ++m)
#pragma unroll
            for (int r = 0; r < 4; ++r) {
                const float p = __expf(s[m][r] - nm);
                s[m][r] = p;
                ls += p;
            }
        ls += __shfl_xor(ls, 16);
        ls += __shfl_xor(ls, 32);
        lrun = lrun * al + ls;
#pragma unroll
        for (int m = 0; m < 4; ++m) o[m] *= al;

        // ---- P -> bf16 -> private LDS (swizzled), re-read as B-frags ----
#pragma unroll
        for (int m = 0; m < 4; ++m) {
            *reinterpret_cast<unsigned*>(myP + ((32 * m + 8 * g) ^ swz)) = pack2(s[m][0], s[m][1]);
            *reinterpret_cast<unsigned*>(myP + ((32 * m + 8 * g + 4) ^ swz)) = pack2(s[m][2], s[m][3]);
        }
        const short8 pf0 = *reinterpret_cast<const short8*>(myP + ((16 * g) ^ swz));
        const short8 pf1 = *reinterpret_cast<const short8*>(myP + ((64 + 16 * g) ^ swz));

        // ---- O^T += V^T . P^T ----
#pragma unroll
        for (int m = 0; m < 4; ++m) {
            const unsigned short* vrow = vb0 + (size_t)(m * 16 + qc) * LL + kt + g * 8;
            short8 va0 = *reinterpret_cast<const short8*>(vrow);
            short8 va1 = *reinterpret_cast<const short8*>(vrow + 32);
            o[m] = __builtin_amdgcn_mfma_f32_16x16x32_bf16(va0, pf0, o[m], 0, 0, 0);
            o[m] = __builtin_amdgcn_mfma_f32_16x16x32_bf16(va1, pf1, o[m], 0, 0, 0);
        }
    }

    // ---- split-K merge: kh=1 publishes, kh=0 combines and writes ----
    if (kh == 1) {
        float* d = Mrg[qh][lane];
#pragma unroll
        for (int m = 0; m < 4; ++m)
#pragma unroll
            for (int r = 0; r < 4; ++r) d[m * 4 + r] = o[m][r];
        d[16] = mrun; d[17] = lrun;
    }
    __syncthreads();
    if (kh == 0) {
        const float* d = Mrg[qh][lane];
        const float m1 = d[16], l1 = d[17];
        const float M = fmaxf(mrun, m1);
        const float a0 = __expf(mrun - M), a1 = __expf(m1 - M);
        const float linv = 1.f / (lrun * a0 + l1 * a1);
        unsigned short* orow = outb + ((size_t)b * LL + gq) * DD + h * DH;
#pragma unroll
        for (int m = 0; m < 4; ++m) {
            ushort4 st;
            st.x = f2b((o[m][0] * a0 + d[m * 4 + 0] * a1) * linv);
            st.y = f2b((o[m][1] * a0 + d[m * 4 + 1] * a1) * linv);
            st.z = f2b((o[m][2] * a0 + d[m * 4 + 2] * a1) * linv);
            st.w = f2b((o[m][3] * a0 + d[m * 4 + 3] * a1) * linv);
            *reinterpret_cast<ushort4*>(orow + m * 16 + g * 4) = st;
        }
    }
}

// ---------------------------------------------------------------------------
// Inputs (dict order): 0 Q, 1 K, 2 V, 3 mask, 4 Wq, 5 bq, 6 Wk, 7 bk,
// 8 Wv, 9 bv, 10 Wo, 11 bo, 12 pos_emb.  Output: [B, L, D] float32.
// 7 dispatches. Workspace (bf16): qbf kbf vT attnb (4 x 4M) + qpos
// [65536][301] + mbits u64[65536] = ~72 MB.
// ---------------------------------------------------------------------------
extern "C" void kernel_launch(void* const* d_in, const int* in_sizes, int n_in,
                              void* d_out, int out_size, void* d_ws, size_t ws_size,
                              hipStream_t stream)
{
    const float* Q  = (const float*)d_in[0];
    const float* K  = (const float*)d_in[1];
    const float* V  = (const float*)d_in[2];
    const int* mask = (const int*)d_in[3];
    const float* Wq = (const float*)d_in[4];
    const float* bq = (const float*)d_in[5];
    const float* Wk = (const float*)d_in[6];
    const float* bk = (const float*)d_in[7];
    const float* Wv = (const float*)d_in[8];
    const float* bv = (const float*)d_in[9];
    const float* Wo = (const float*)d_in[10];
    const float* bo = (const float*)d_in[11];
    const float* pe = (const float*)d_in[12];
    float* out = (float*)d_out;

    unsigned short* ws = (unsigned short*)d_ws;
    const size_t NQ = (size_t)BB * HH * LL * DH;       // 4,194,304
    unsigned short* qbf = ws;
    unsigned short* kbf = qbf + NQ;
    unsigned short* vT  = kbf + NQ;
    unsigned short* attnb = vT + NQ;
    unsigned short* qpos = attnb + NQ;                 // bf16 [65536][301]
    unsigned long long* mbits =
        (unsigned long long*)(qpos + (size_t)BB * HH * LL * NPOS);

    const dim3 blk(256);
    const int M = BB * LL;                             // 4096

    pack_mask<<<dim3((BB * LL * LL / 64) * 64 / 256), blk, 0, stream>>>(mask, mbits);
    gemm_mfma<1, false, true, true><<<dim3(16, 32), blk, 0, stream>>>(
        Q, Wq, bq, qbf, M, DD, DD, 0.125f);
    gemm_mfma<1, false, true, true><<<dim3(16, 32), blk, 0, stream>>>(
        K, Wk, bk, kbf, M, DD, DD, 1.0f);
    gemm_mfma<2, false, true, true><<<dim3(16, 32), blk, 0, stream>>>(
        V, Wv, bv, vT, M, DD, DD, 1.0f);
    gemm_mfma<3, true, false, true><<<dim3(5, 512), blk, 0, stream>>>(
        qbf, pe, nullptr, qpos, BB * HH * LL, NPOS, DH, 1.0f);
    attn_mfma<<<dim3(BB * HH, LL / 32), dim3(256), 0, stream>>>(
        qbf, kbf, vT, qpos, mbits, attnb);
    gemm_mfma<0, false, false, true><<<dim3(16, 32), blk, 0, stream>>>(
        attnb, Wo, bo, out, M, DD, DD, 1.0f);
}

// Round 14
// 302.622 us; speedup vs baseline: 1.3519x; 1.3519x over previous
//
#include <hip/hip_runtime.h>
#include <hip/hip_bf16.h>

// Problem constants (B=4, L=1024, D=1024, H=16, Dh=64, MAX_LEN=150)
#define BB 4
#define LL 1024
#define DD 1024
#define HH 16
#define DH 64
#define NPOS 301      // 2*MAX_LEN+1
#define MAXL 150
#define NEG_INF -1e30f

typedef __attribute__((ext_vector_type(4))) float f32x4;
typedef __attribute__((ext_vector_type(8))) short short8;

__device__ inline unsigned short f2b(float x) {
    __hip_bfloat16 h = __float2bfloat16(x);
    return *reinterpret_cast<unsigned short*>(&h);
}
__device__ inline unsigned pack2(float a, float b) {
    return (unsigned)f2b(a) | ((unsigned)f2b(b) << 16);
}
__device__ inline float b2f(unsigned short u) {
    return __uint_as_float((unsigned)u << 16);
}

// Load 8 contiguous elements as bf16x8, converting from f32 when F32=true.
template <bool F32>
__device__ inline short8 ld8(const void* p, size_t off) {
    if constexpr (F32) {
        const float* q = (const float*)p + off;
        float4 a = *reinterpret_cast<const float4*>(q);
        float4 b = *reinterpret_cast<const float4*>(q + 4);
        short8 r;
        r[0] = (short)f2b(a.x); r[1] = (short)f2b(a.y);
        r[2] = (short)f2b(a.z); r[3] = (short)f2b(a.w);
        r[4] = (short)f2b(b.x); r[5] = (short)f2b(b.y);
        r[6] = (short)f2b(b.z); r[7] = (short)f2b(b.w);
        return r;
    } else {
        return *reinterpret_cast<const short8*>((const unsigned short*)p + off);
    }
}

// ---------------------------------------------------------------------------
// Mask bit-pack: mask[b][q][k] (nonzero = masked) -> one bit per element.
// ---------------------------------------------------------------------------
__global__ __launch_bounds__(256) void pack_mask(const int* __restrict__ mask,
                                                 unsigned long long* __restrict__ bits)
{
    const int wid = (blockIdx.x * 256 + threadIdx.x) >> 6;   // global wave id
    const int lane = threadIdx.x & 63;
    const int v = mask[(size_t)wid * 64 + lane];
    const unsigned long long b = __ballot(v != 0);
    if (lane == 0) bits[wid] = b;
}

// ---------------------------------------------------------------------------
// bf16 MFMA GEMM: C = (A @ W^T + bias) * oscale.  (validated rounds 7-13)
// A/W may be f32 -- converted to bf16 in-register during LDS staging.
// Tile 128(M) x 64(N), BK=32, 4 waves (2x2), wave owns 64x32; padded LDS.
// EPI 0: f32 [M][N]; EPI 1: bf16 [bh][l][dh]; EPI 2: bf16 [bh][dh][l];
// EPI 3: bf16 plain [M][N] (GN guards N).
// ---------------------------------------------------------------------------
template <int EPI, bool GN, bool AF32, bool WF32>
__global__ __launch_bounds__(256) void gemm_mfma(
    const void* __restrict__ A, const void* __restrict__ W,
    const float* __restrict__ bias, void* __restrict__ Cout,
    int M, int N, int K, float oscale)
{
    __shared__ alignas(16) unsigned short As[128 * 40];
    __shared__ alignas(16) unsigned short Bs[64 * 40];
    const int tid = threadIdx.x;
    const int w = tid >> 6, lane = tid & 63;
    const int wr = w >> 1, wc = w & 1;
    const int g = lane >> 4, fr = lane & 15;
    const int m0 = blockIdx.y * 128;
    const int n0 = blockIdx.x * 64;

    f32x4 acc[4][2];
#pragma unroll
    for (int i = 0; i < 4; ++i)
#pragma unroll
        for (int j = 0; j < 2; ++j) acc[i][j] = (f32x4){0.f, 0.f, 0.f, 0.f};

    const int arow0 = tid >> 2, agg = tid & 3;
    for (int k0 = 0; k0 < K; k0 += 32) {
        {
            short8 v0 = ld8<AF32>(A, (size_t)(m0 + arow0) * K + k0 + agg * 8);
            short8 v1 = ld8<AF32>(A, (size_t)(m0 + arow0 + 64) * K + k0 + agg * 8);
            int nr = n0 + arow0;
            if (GN && nr >= N) nr = N - 1;
            short8 bv = ld8<WF32>(W, (size_t)nr * K + k0 + agg * 8);
            *reinterpret_cast<short8*>(&As[arow0 * 40 + agg * 8]) = v0;
            *reinterpret_cast<short8*>(&As[(arow0 + 64) * 40 + agg * 8]) = v1;
            *reinterpret_cast<short8*>(&Bs[arow0 * 40 + agg * 8]) = bv;
        }
        __syncthreads();
        short8 af[4], bf[2];
#pragma unroll
        for (int i = 0; i < 4; ++i)
            af[i] = *reinterpret_cast<const short8*>(
                &As[(wr * 64 + i * 16 + fr) * 40 + g * 8]);
#pragma unroll
        for (int j = 0; j < 2; ++j)
            bf[j] = *reinterpret_cast<const short8*>(
                &Bs[(wc * 32 + j * 16 + fr) * 40 + g * 8]);
#pragma unroll
        for (int i = 0; i < 4; ++i)
#pragma unroll
            for (int j = 0; j < 2; ++j)
                acc[i][j] = __builtin_amdgcn_mfma_f32_16x16x32_bf16(
                    af[i], bf[j], acc[i][j], 0, 0, 0);
        __syncthreads();
    }

#pragma unroll
    for (int i = 0; i < 4; ++i) {
#pragma unroll
        for (int j = 0; j < 2; ++j) {
#pragma unroll
            for (int r = 0; r < 4; ++r) {
                const int row = m0 + wr * 64 + i * 16 + g * 4 + r;
                const int col = n0 + wc * 32 + j * 16 + fr;
                if (GN && col >= N) continue;
                const float val = (acc[i][j][r] + (bias ? bias[col] : 0.f)) * oscale;
                if (EPI == 0) {
                    ((float*)Cout)[(size_t)row * N + col] = val;
                } else if (EPI == 1) {
                    const int b = row >> 10, l = row & 1023, hh = col >> 6, dh = col & 63;
                    ((unsigned short*)Cout)[(((size_t)(b * HH + hh)) * LL + l) * DH + dh] = f2b(val);
                } else if (EPI == 2) {
                    const int b = row >> 10, l = row & 1023, hh = col >> 6, dh = col & 63;
                    ((unsigned short*)Cout)[(((size_t)(b * HH + hh)) * DH + dh) * LL + l] = f2b(val);
                } else {
                    ((unsigned short*)Cout)[(size_t)row * N + col] = f2b(val);
                }
            }
        }
    }
}

// ---------------------------------------------------------------------------
// MFMA attention, round 14. r13's (256,8) pin REVERTED (VGPR 32 -> spills,
// FETCH 358 MB). Structure = r12 split-K (2 q-groups x 2 k-halves, 8 tiles
// per wave). NEW: the block's 32 qpos rows (32x301 bf16 = 19.3 KB) are
// bulk-staged COALESCED into LDS once; the in-band gather becomes ds_read_u16
// (was ~5 cold-HBM 600B-stride scalar loads per lane per tile -- the dominant
// latency). The split-K merge buffer ALIASES the slab (disjoint lifetimes,
// barrier-separated), so LDS = 8 KB Plds + 19.3 KB = 27.5 KB -> 5 blocks/CU.
// ---------------------------------------------------------------------------
__global__ __launch_bounds__(256) void attn_mfma(
    const unsigned short* __restrict__ qbf,   // [bh][l][dh] bf16 (scaled 1/8)
    const unsigned short* __restrict__ kbf,   // [bh][l][dh] bf16
    const unsigned short* __restrict__ vT,    // [bh][dh][l] bf16
    const unsigned short* __restrict__ qpos,  // [bh*L][301] bf16 (scaled 1/8)
    const unsigned long long* __restrict__ mbits, // [b][q][L/64] bit-mask
    unsigned short* __restrict__ outb)        // [b][l][D] bf16
{
    const int bh = blockIdx.x;                // fast dim -> same-bh on one XCD
    const int qblk = blockIdx.y;
    const int b = bh >> 4, h = bh & 15;
    const int tid = threadIdx.x;
    const int w = tid >> 6;                   // 0..3
    const int qh = w & 1;                     // q-group
    const int kh = w >> 1;                    // k-half
    const int lane = tid & 63;
    const int g = lane >> 4;
    const int qc = lane & 15;
    const int gq = qblk * 32 + qh * 16 + qc;
    const int ql = qh * 16 + qc;              // local q row (0..31)

    __shared__ alignas(16) unsigned char Plds[4 * 2048];
    __shared__ alignas(16) unsigned short Qp[32 * NPOS];   // 19264 B; aliased
    float* Mrg = (float*)Qp;                  // as merge buf after 2nd barrier
    unsigned char* myP = Plds + w * 2048 + qc * 128;
    const int swz = (qc & 7) << 4;

    // ---- stage qpos slab (contiguous 32*301 bf16), coalesced ----
    {
        const unsigned short* qslab = qpos + ((size_t)bh * LL + (size_t)qblk * 32) * NPOS;
        for (int i = tid; i < (32 * NPOS) / 8; i += 256)   // 1204 short8 chunks
            *reinterpret_cast<short8*>(&Qp[i * 8]) =
                *reinterpret_cast<const short8*>(qslab + (size_t)i * 8);
    }

    const unsigned short* qrow = qbf + ((size_t)bh * LL + gq) * DH;
    const short8 qf0 = *reinterpret_cast<const short8*>(qrow + g * 8);
    const short8 qf1 = *reinterpret_cast<const short8*>(qrow + g * 8 + 32);

    const unsigned short* kb0 = kbf + (size_t)bh * LL * DH;
    const unsigned short* vb0 = vT + (size_t)bh * DH * LL;
    const unsigned long long* mwp = mbits + ((size_t)b * LL + gq) * (LL / 64);
    const unsigned short* qpr = &Qp[ql * NPOS];

    float mrun = -3.0e38f, lrun = 0.f;
    f32x4 o[4];
#pragma unroll
    for (int m = 0; m < 4; ++m) o[m] = (f32x4){0.f, 0.f, 0.f, 0.f};

    __syncthreads();                          // Qp ready (read-only in loop)
    const float c_left = b2f(qpr[300]);       // rel <= -150
    const float c_right = b2f(qpr[299]);      // rel >= +150

    // 8 tiles per wave, interleaved across k-halves
    for (int it = 0; it < 8; ++it) {
        const int kt = kh * 64 + it * 128;

        // ---- S^T = K . Q^T ----
        f32x4 s[4];
#pragma unroll
        for (int m = 0; m < 4; ++m) s[m] = (f32x4){0.f, 0.f, 0.f, 0.f};
#pragma unroll
        for (int m = 0; m < 4; ++m) {
            const unsigned short* krow = kb0 + (size_t)(kt + m * 16 + qc) * DH + g * 8;
            short8 a0 = *reinterpret_cast<const short8*>(krow);
            short8 a1 = *reinterpret_cast<const short8*>(krow + 32);
            s[m] = __builtin_amdgcn_mfma_f32_16x16x32_bf16(a0, qf0, s[m], 0, 0, 0);
            s[m] = __builtin_amdgcn_mfma_f32_16x16x32_bf16(a1, qf1, s[m], 0, 0, 0);
        }

        // ---- scores in place: banded qpos (LDS) + bit-mask ----
        const unsigned long long mw = mwp[kt >> 6];
        float tmax = -3.0e38f;
#pragma unroll
        for (int m = 0; m < 4; ++m) {
            const int kb = kt + m * 16 + g * 4;
            const unsigned msub = (unsigned)(mw >> (m * 16 + g * 4)) & 0xFu;
            const int p0 = kb - gq + 149;     // unclipped idx of r=0
            float rp0, rp1, rp2, rp3;
            if (p0 > 299) {                   // whole run right-saturated
                rp0 = rp1 = rp2 = rp3 = c_right;
            } else if (p0 < -3) {             // whole run left-saturated
                rp0 = rp1 = rp2 = rp3 = c_left;
            } else if (p0 >= 0 && p0 <= 296) { // strictly in band (LDS reads)
                rp0 = b2f(qpr[p0]);     rp1 = b2f(qpr[p0 + 1]);
                rp2 = b2f(qpr[p0 + 2]); rp3 = b2f(qpr[p0 + 3]);
            } else {                          // straddling band edge (rare)
                int i0 = p0 < 0 ? 300 : p0;
                int i1 = p0 + 1 < 0 ? 300 : (p0 + 1 > 299 ? 299 : p0 + 1);
                int i2 = p0 + 2 < 0 ? 300 : (p0 + 2 > 299 ? 299 : p0 + 2);
                int i3 = p0 + 3 > 299 ? 299 : p0 + 3;
                rp0 = b2f(qpr[i0]); rp1 = b2f(qpr[i1]);
                rp2 = b2f(qpr[i2]); rp3 = b2f(qpr[i3]);
            }
#pragma unroll
            for (int r = 0; r < 4; ++r) {
                const float rp = (r == 0 ? rp0 : r == 1 ? rp1 : r == 2 ? rp2 : rp3);
                float x = s[m][r] + rp;       // both pre-scaled by 1/8
                x = (msub >> r) & 1 ? NEG_INF : x;
                s[m][r] = x;
                tmax = fmaxf(tmax, x);
            }
        }

        // ---- online softmax (in-register, in-place exp) ----
        tmax = fmaxf(tmax, __shfl_xor(tmax, 16));
        tmax = fmaxf(tmax, __shfl_xor(tmax, 32));
        const float nm = fmaxf(mrun, tmax);
        const float al = __expf(mrun - nm);
        mrun = nm;
        float ls = 0.f;
#pragma unroll
        for (int m = 0; m < 4; ++m)
#pragma unroll
            for (int r = 0; r < 4; ++r) {
                const float p = __expf(s[m][r] - nm);
                s[m][r] = p;
                ls += p;
            }
        ls += __shfl_xor(ls, 16);
        ls += __shfl_xor(ls, 32);
        lrun = lrun * al + ls;
#pragma unroll
        for (int m = 0; m < 4; ++m) o[m] *= al;

        // ---- P -> bf16 -> private LDS (swizzled), re-read as B-frags ----
#pragma unroll
        for (int m = 0; m < 4; ++m) {
            *reinterpret_cast<unsigned*>(myP + ((32 * m + 8 * g) ^ swz)) = pack2(s[m][0], s[m][1]);
            *reinterpret_cast<unsigned*>(myP + ((32 * m + 8 * g + 4) ^ swz)) = pack2(s[m][2], s[m][3]);
        }
        const short8 pf0 = *reinterpret_cast<const short8*>(myP + ((16 * g) ^ swz));
        const short8 pf1 = *reinterpret_cast<const short8*>(myP + ((64 + 16 * g) ^ swz));

        // ---- O^T += V^T . P^T ----
#pragma unroll
        for (int m = 0; m < 4; ++m) {
            const unsigned short* vrow = vb0 + (size_t)(m * 16 + qc) * LL + kt + g * 8;
            short8 va0 = *reinterpret_cast<const short8*>(vrow);
            short8 va1 = *reinterpret_cast<const short8*>(vrow + 32);
            o[m] = __builtin_amdgcn_mfma_f32_16x16x32_bf16(va0, pf0, o[m], 0, 0, 0);
            o[m] = __builtin_amdgcn_mfma_f32_16x16x32_bf16(va1, pf1, o[m], 0, 0, 0);
        }
    }

    // ---- split-K merge (Mrg aliases Qp; barrier separates lifetimes) ----
    __syncthreads();                          // everyone done reading Qp
    if (kh == 1) {
        float* d = Mrg + ((size_t)qh * 64 + lane) * 18;
#pragma unroll
        for (int m = 0; m < 4; ++m)
#pragma unroll
            for (int r = 0; r < 4; ++r) d[m * 4 + r] = o[m][r];
        d[16] = mrun; d[17] = lrun;
    }
    __syncthreads();
    if (kh == 0) {
        const float* d = Mrg + ((size_t)qh * 64 + lane) * 18;
        const float m1 = d[16], l1 = d[17];
        const float M = fmaxf(mrun, m1);
        const float a0 = __expf(mrun - M), a1 = __expf(m1 - M);
        const float linv = 1.f / (lrun * a0 + l1 * a1);
        unsigned short* orow = outb + ((size_t)b * LL + gq) * DD + h * DH;
#pragma unroll
        for (int m = 0; m < 4; ++m) {
            ushort4 st;
            st.x = f2b((o[m][0] * a0 + d[m * 4 + 0] * a1) * linv);
            st.y = f2b((o[m][1] * a0 + d[m * 4 + 1] * a1) * linv);
            st.z = f2b((o[m][2] * a0 + d[m * 4 + 2] * a1) * linv);
            st.w = f2b((o[m][3] * a0 + d[m * 4 + 3] * a1) * linv);
            *reinterpret_cast<ushort4*>(orow + m * 16 + g * 4) = st;
        }
    }
}

// ---------------------------------------------------------------------------
// Inputs (dict order): 0 Q, 1 K, 2 V, 3 mask, 4 Wq, 5 bq, 6 Wk, 7 bk,
// 8 Wv, 9 bv, 10 Wo, 11 bo, 12 pos_emb.  Output: [B, L, D] float32.
// 7 dispatches. Workspace (bf16): qbf kbf vT attnb (4 x 4M) + qpos
// [65536][301] + mbits u64[65536] = ~72 MB.
// ---------------------------------------------------------------------------
extern "C" void kernel_launch(void* const* d_in, const int* in_sizes, int n_in,
                              void* d_out, int out_size, void* d_ws, size_t ws_size,
                              hipStream_t stream)
{
    const float* Q  = (const float*)d_in[0];
    const float* K  = (const float*)d_in[1];
    const float* V  = (const float*)d_in[2];
    const int* mask = (const int*)d_in[3];
    const float* Wq = (const float*)d_in[4];
    const float* bq = (const float*)d_in[5];
    const float* Wk = (const float*)d_in[6];
    const float* bk = (const float*)d_in[7];
    const float* Wv = (const float*)d_in[8];
    const float* bv = (const float*)d_in[9];
    const float* Wo = (const float*)d_in[10];
    const float* bo = (const float*)d_in[11];
    const float* pe = (const float*)d_in[12];
    float* out = (float*)d_out;

    unsigned short* ws = (unsigned short*)d_ws;
    const size_t NQ = (size_t)BB * HH * LL * DH;       // 4,194,304
    unsigned short* qbf = ws;
    unsigned short* kbf = qbf + NQ;
    unsigned short* vT  = kbf + NQ;
    unsigned short* attnb = vT + NQ;
    unsigned short* qpos = attnb + NQ;                 // bf16 [65536][301]
    unsigned long long* mbits =
        (unsigned long long*)(qpos + (size_t)BB * HH * LL * NPOS);

    const dim3 blk(256);
    const int M = BB * LL;                             // 4096

    pack_mask<<<dim3((BB * LL * LL / 64) * 64 / 256), blk, 0, stream>>>(mask, mbits);
    gemm_mfma<1, false, true, true><<<dim3(16, 32), blk, 0, stream>>>(
        Q, Wq, bq, qbf, M, DD, DD, 0.125f);
    gemm_mfma<1, false, true, true><<<dim3(16, 32), blk, 0, stream>>>(
        K, Wk, bk, kbf, M, DD, DD, 1.0f);
    gemm_mfma<2, false, true, true><<<dim3(16, 32), blk, 0, stream>>>(
        V, Wv, bv, vT, M, DD, DD, 1.0f);
    gemm_mfma<3, true, false, true><<<dim3(5, 512), blk, 0, stream>>>(
        qbf, pe, nullptr, qpos, BB * HH * LL, NPOS, DH, 1.0f);
    attn_mfma<<<dim3(BB * HH, LL / 32), dim3(256), 0, stream>>>(
        qbf, kbf, vT, qpos, mbits, attnb);
    gemm_mfma<0, false, false, true><<<dim3(16, 32), blk, 0, stream>>>(
        attnb, Wo, bo, out, M, DD, DD, 1.0f);
}